// Round 1
// baseline (486.688 us; speedup 1.0000x reference)
//
#include <hip/hip_runtime.h>
#include <hip/hip_bf16.h>

#define D 64           // feature dim
#define CLAMP_V -10000.0f

// ---- float <-> order-preserving uint mapping for atomic max ----
__device__ __forceinline__ unsigned ord_encode(float v) {
    unsigned u = __float_as_uint(v);
    return (u & 0x80000000u) ? ~u : (u | 0x80000000u);
}
__device__ __forceinline__ float ord_decode(unsigned o) {
    unsigned u = (o & 0x80000000u) ? (o ^ 0x80000000u) : ~o;
    return __uint_as_float(u);
}

// One wave (64 lanes) per edge; lane = feature dim.
// Coalesced 256B gathers of src/dst rows, coalesced atomics onto agg[dst].
__global__ __launch_bounds__(256) void edge_scatter_max(
        const float* __restrict__ nf,
        const int* __restrict__ src,
        const int* __restrict__ dst,
        unsigned* __restrict__ agg,
        int nE) {
    int gtid = blockIdx.x * blockDim.x + threadIdx.x;
    int e    = gtid >> 6;          // wave id = edge id
    int lane = gtid & 63;
    if (e >= nE) return;
    int s = src[e];
    int d = dst[e];
    float v = nf[(size_t)s * D + lane] - nf[(size_t)d * D + lane];
    atomicMax(&agg[(size_t)d * D + lane], ord_encode(v));
}

// One wave per node: lane j computes out[n][j] = relu(b[j] + sum_k h[k]*W[k][j])
// W (128x64 = 32KB) staged in LDS once per block; h (128) staged per wave.
__global__ __launch_bounds__(256) void node_mlp(
        const float* __restrict__ nf,
        const unsigned* __restrict__ agg,
        const float* __restrict__ W,
        const float* __restrict__ bias,
        float* __restrict__ out,
        int nN) {
    __shared__ float Wl[2 * D * D];     // [128][64] = 32 KB
    __shared__ float hl[4][2 * D];      // per-wave h vector, 2 KB

    int tid  = threadIdx.x;
    int wave = tid >> 6;
    int lane = tid & 63;

    // cooperative W load (coalesced, 32 floats per thread)
    #pragma unroll
    for (int i = tid; i < 2 * D * D; i += 256) Wl[i] = W[i];

    int n = blockIdx.x * 4 + wave;
    bool valid = n < nN;
    if (valid) {
        float x0 = nf[(size_t)n * D + lane];
        float a  = ord_decode(agg[(size_t)n * D + lane]);
        // empty slot decodes to NaN -> (a >= CLAMP) false -> 0; matches ref
        a = (a >= CLAMP_V) ? a : 0.0f;
        hl[wave][lane]     = x0;
        hl[wave][D + lane] = a;
    }
    __syncthreads();

    if (valid) {
        float acc = bias[lane];
        #pragma unroll
        for (int k = 0; k < 2 * D; ++k) {
            acc = fmaf(hl[wave][k], Wl[k * D + lane], acc);
        }
        out[(size_t)n * D + lane] = fmaxf(acc, 0.0f);
    }
}

extern "C" void kernel_launch(void* const* d_in, const int* in_sizes, int n_in,
                              void* d_out, int out_size, void* d_ws, size_t ws_size,
                              hipStream_t stream) {
    const float* nf  = (const float*)d_in[0];
    const int*   src = (const int*)d_in[1];
    const int*   dst = (const int*)d_in[2];
    const float* W   = (const float*)d_in[3];
    const float* b   = (const float*)d_in[4];
    float* out = (float*)d_out;

    int nN = in_sizes[0] / D;
    int nE = in_sizes[1];

    unsigned* agg = (unsigned*)d_ws;     // nN * 64 * 4 bytes = 25.6 MB

    // ord=0 decodes to -NaN => clamped to 0 later (empty-segment semantics)
    hipMemsetAsync(agg, 0, (size_t)nN * D * sizeof(unsigned), stream);

    // edge pass: one wave per edge
    {
        long long threads = (long long)nE * 64;
        int block = 256;
        int grid = (int)((threads + block - 1) / block);
        edge_scatter_max<<<grid, block, 0, stream>>>(nf, src, dst, agg, nE);
    }
    // node pass: one wave per node, 4 nodes per block
    {
        int block = 256;
        int grid = (nN + 3) / 4;
        node_mlp<<<grid, block, 0, stream>>>(nf, agg, W, b, out, nN);
    }
}

// Round 2
// 441.310 us; speedup vs baseline: 1.1028x; 1.1028x over previous
//
#include <hip/hip_runtime.h>
#include <hip/hip_bf16.h>

#define D 64
#define CLAMP_V -10000.0f

// ---------- pass 1: histogram of dst ----------
__global__ __launch_bounds__(256) void hist_kernel(
        const int* __restrict__ dst, unsigned* __restrict__ hist, int nE) {
    int e = blockIdx.x * blockDim.x + threadIdx.x;
    if (e < nE) atomicAdd(&hist[dst[e]], 1u);
}

// ---------- pass 2a: per-block partial sums (block = 4096 bins) ----------
__global__ __launch_bounds__(256) void scan_partials(
        const unsigned* __restrict__ hist, unsigned* __restrict__ partials, int nTot) {
    __shared__ unsigned ts[256];
    int t = threadIdx.x;
    int base = blockIdx.x * 4096;
    unsigned s = 0;
    #pragma unroll
    for (int i = 0; i < 16; ++i) {
        int idx = base + i * 256 + t;
        if (idx < nTot) s += hist[idx];
    }
    ts[t] = s; __syncthreads();
    for (int off = 128; off > 0; off >>= 1) {
        if (t < off) ts[t] += ts[t + off];
        __syncthreads();
    }
    if (t == 0) partials[blockIdx.x] = ts[0];
}

// ---------- pass 2b: exclusive scan, write cursor ----------
__global__ __launch_bounds__(256) void scan_write(
        const unsigned* __restrict__ hist, const unsigned* __restrict__ partials,
        unsigned* __restrict__ cursor, int nTot, int nb) {
    __shared__ unsigned ts[256];
    int t = threadIdx.x;
    int b = blockIdx.x;
    // prefix of preceding blocks
    unsigned pre = 0;
    for (int j = 0; j < nb; ++j) if (j < b) pre += partials[j];
    // thread-local contiguous chunk of 16
    int base = b * 4096 + t * 16;
    unsigned v[16], tsum = 0;
    #pragma unroll
    for (int i = 0; i < 16; ++i) {
        int idx = base + i;
        v[i] = (idx < nTot) ? hist[idx] : 0u;
        tsum += v[i];
    }
    ts[t] = tsum; __syncthreads();
    // Hillis-Steele inclusive scan of 256 thread sums
    for (int off = 1; off < 256; off <<= 1) {
        unsigned x = (t >= off) ? ts[t - off] : 0u;
        __syncthreads();
        ts[t] += x;
        __syncthreads();
    }
    unsigned run = pre + ts[t] - tsum;   // exclusive start for this thread
    #pragma unroll
    for (int i = 0; i < 16; ++i) {
        int idx = base + i;
        if (idx < nTot) cursor[idx] = run;
        run += v[i];
    }
}

// ---------- pass 3: scatter src into dst-sorted order ----------
__global__ __launch_bounds__(256) void scatter_kernel(
        const int* __restrict__ src, const int* __restrict__ dst,
        unsigned* __restrict__ cursor, int* __restrict__ ssrc, int nE) {
    int e = blockIdx.x * blockDim.x + threadIdx.x;
    if (e < nE) {
        int d = dst[e];
        unsigned pos = atomicAdd(&cursor[d], 1u);
        ssrc[pos] = src[e];
    }
}

// ---------- pass 4: segmented max, one wave per node ----------
// after scatter: cursor[n] == segment_end(n); segment_beg(n) = cursor[n-1] (0 for n=0)
__global__ __launch_bounds__(256) void segmax_kernel(
        const float* __restrict__ nf, const int* __restrict__ ssrc,
        const unsigned* __restrict__ cursor, float* __restrict__ agg, int nN) {
    int gtid = blockIdx.x * blockDim.x + threadIdx.x;
    int n    = gtid >> 6;
    int lane = gtid & 63;
    if (n >= nN) return;
    int beg = (n == 0) ? 0 : (int)cursor[n - 1];
    int end = (int)cursor[n];
    float xd = nf[(size_t)n * D + lane];
    float m = -INFINITY;
    int e = beg;
    for (; e + 4 <= end; e += 4) {
        int s0 = ssrc[e], s1 = ssrc[e + 1], s2 = ssrc[e + 2], s3 = ssrc[e + 3];
        float v0 = nf[(size_t)s0 * D + lane];
        float v1 = nf[(size_t)s1 * D + lane];
        float v2 = nf[(size_t)s2 * D + lane];
        float v3 = nf[(size_t)s3 * D + lane];
        m = fmaxf(m, fmaxf(fmaxf(v0, v1), fmaxf(v2, v3)));
    }
    for (; e < end; ++e) m = fmaxf(m, nf[(size_t)ssrc[e] * D + lane]);
    float r = m - xd;                       // max(v - x) = max(v) - x
    agg[(size_t)n * D + lane] = (r >= CLAMP_V) ? r : 0.0f;  // -inf (empty) -> 0
}

// ---------- pass 5: MLP (agg staged in-place in d_out) ----------
__global__ __launch_bounds__(256) void node_mlp(
        const float* __restrict__ nf,
        float* agg_out,                 // reads agg row n, overwrites with out row n
        const float* __restrict__ W,
        const float* __restrict__ bias,
        int nN) {
    __shared__ float Wl[2 * D * D];     // 32 KB
    __shared__ float hl[4][2 * D];

    int tid  = threadIdx.x;
    int wave = tid >> 6;
    int lane = tid & 63;

    #pragma unroll
    for (int i = tid; i < 2 * D * D; i += 256) Wl[i] = W[i];

    int n = blockIdx.x * 4 + wave;
    bool valid = n < nN;
    if (valid) {
        hl[wave][lane]     = nf[(size_t)n * D + lane];
        hl[wave][D + lane] = agg_out[(size_t)n * D + lane];  // pre-clamped
    }
    __syncthreads();

    if (valid) {
        float acc = bias[lane];
        #pragma unroll
        for (int k = 0; k < 2 * D; ++k) {
            acc = fmaf(hl[wave][k], Wl[k * D + lane], acc);
        }
        agg_out[(size_t)n * D + lane] = fmaxf(acc, 0.0f);
    }
}

extern "C" void kernel_launch(void* const* d_in, const int* in_sizes, int n_in,
                              void* d_out, int out_size, void* d_ws, size_t ws_size,
                              hipStream_t stream) {
    const float* nf  = (const float*)d_in[0];
    const int*   src = (const int*)d_in[1];
    const int*   dst = (const int*)d_in[2];
    const float* W   = (const float*)d_in[3];
    const float* b   = (const float*)d_in[4];
    float* out = (float*)d_out;

    int nN = in_sizes[0] / D;
    int nE = in_sizes[1];
    int nTot = nN + 1;
    int nb = (nTot + 4095) / 4096;      // scan blocks

    // ws layout
    size_t hAlign = ((size_t)nTot * 4 + 255) & ~(size_t)255;
    char* wsb = (char*)d_ws;
    unsigned* hist     = (unsigned*)wsb;
    unsigned* cursor   = (unsigned*)(wsb + hAlign);
    unsigned* partials = (unsigned*)(wsb + 2 * hAlign);
    int*      ssrc     = (int*)(wsb + 2 * hAlign + 4096);

    hipMemsetAsync(hist, 0, (size_t)nTot * 4, stream);

    int gE = (nE + 255) / 256;
    hist_kernel<<<gE, 256, 0, stream>>>(dst, hist, nE);
    scan_partials<<<nb, 256, 0, stream>>>(hist, partials, nTot);
    scan_write<<<nb, 256, 0, stream>>>(hist, partials, cursor, nTot, nb);
    scatter_kernel<<<gE, 256, 0, stream>>>(src, dst, cursor, ssrc, nE);

    // agg staged in d_out (segmax fully overwrites it; no init needed)
    segmax_kernel<<<(nN + 3) / 4, 256, 0, stream>>>(nf, ssrc, cursor, out, nN);
    node_mlp<<<(nN + 3) / 4, 256, 0, stream>>>(nf, out, W, b, nN);
}

// Round 3
// 386.098 us; speedup vs baseline: 1.2605x; 1.1430x over previous
//
#include <hip/hip_runtime.h>
#include <hip/hip_bf16.h>

#define D 64
#define CLAMP_V -10000.0f

typedef __bf16 bf16x8 __attribute__((ext_vector_type(8)));
typedef float floatx4 __attribute__((ext_vector_type(4)));

// ---------- pass 1: histogram of dst ----------
__global__ __launch_bounds__(256) void hist_kernel(
        const int* __restrict__ dst, unsigned* __restrict__ hist, int nE) {
    int e = blockIdx.x * blockDim.x + threadIdx.x;
    if (e < nE) atomicAdd(&hist[dst[e]], 1u);
}

// ---------- pass 2a: per-block partial sums (block = 4096 bins) ----------
__global__ __launch_bounds__(256) void scan_partials(
        const unsigned* __restrict__ hist, unsigned* __restrict__ partials, int nTot) {
    __shared__ unsigned ts[256];
    int t = threadIdx.x;
    int base = blockIdx.x * 4096;
    unsigned s = 0;
    #pragma unroll
    for (int i = 0; i < 16; ++i) {
        int idx = base + i * 256 + t;
        if (idx < nTot) s += hist[idx];
    }
    ts[t] = s; __syncthreads();
    for (int off = 128; off > 0; off >>= 1) {
        if (t < off) ts[t] += ts[t + off];
        __syncthreads();
    }
    if (t == 0) partials[blockIdx.x] = ts[0];
}

// ---------- pass 2b: exclusive scan, write cursor ----------
__global__ __launch_bounds__(256) void scan_write(
        const unsigned* __restrict__ hist, const unsigned* __restrict__ partials,
        unsigned* __restrict__ cursor, int nTot, int nb) {
    __shared__ unsigned ts[256];
    int t = threadIdx.x;
    int b = blockIdx.x;
    unsigned pre = 0;
    for (int j = 0; j < nb; ++j) if (j < b) pre += partials[j];
    int base = b * 4096 + t * 16;
    unsigned v[16], tsum = 0;
    #pragma unroll
    for (int i = 0; i < 16; ++i) {
        int idx = base + i;
        v[i] = (idx < nTot) ? hist[idx] : 0u;
        tsum += v[i];
    }
    ts[t] = tsum; __syncthreads();
    for (int off = 1; off < 256; off <<= 1) {
        unsigned x = (t >= off) ? ts[t - off] : 0u;
        __syncthreads();
        ts[t] += x;
        __syncthreads();
    }
    unsigned run = pre + ts[t] - tsum;
    #pragma unroll
    for (int i = 0; i < 16; ++i) {
        int idx = base + i;
        if (idx < nTot) cursor[idx] = run;
        run += v[i];
    }
}

// ---------- pass 3: scatter src into dst-sorted order ----------
// atomicExch for the data store: memory-side 4B write, no cache-line
// allocation (R2 evidence: plain scattered stores cost 64B/line -> 106MB;
// atomics cost exactly 4B).
__global__ __launch_bounds__(256) void scatter_kernel(
        const int* __restrict__ src, const int* __restrict__ dst,
        unsigned* __restrict__ cursor, int* __restrict__ ssrc, int nE) {
    int e = blockIdx.x * blockDim.x + threadIdx.x;
    if (e < nE) {
        int d = dst[e];
        unsigned pos = atomicAdd(&cursor[d], 1u);
        atomicExch(&ssrc[pos], src[e]);
    }
}

// ---------- pass 4: segmented max, one wave per node ----------
__global__ __launch_bounds__(256) void segmax_kernel(
        const float* __restrict__ nf, const int* __restrict__ ssrc,
        const unsigned* __restrict__ cursor, float* __restrict__ agg, int nN) {
    int gtid = blockIdx.x * blockDim.x + threadIdx.x;
    int n    = gtid >> 6;
    int lane = gtid & 63;
    if (n >= nN) return;
    int beg = (n == 0) ? 0 : (int)cursor[n - 1];
    int end = (int)cursor[n];
    float xd = nf[(size_t)n * D + lane];
    float m = -INFINITY;
    int e = beg;
    for (; e + 4 <= end; e += 4) {
        int s0 = ssrc[e], s1 = ssrc[e + 1], s2 = ssrc[e + 2], s3 = ssrc[e + 3];
        float v0 = nf[(size_t)s0 * D + lane];
        float v1 = nf[(size_t)s1 * D + lane];
        float v2 = nf[(size_t)s2 * D + lane];
        float v3 = nf[(size_t)s3 * D + lane];
        m = fmaxf(m, fmaxf(fmaxf(v0, v1), fmaxf(v2, v3)));
    }
    for (; e < end; ++e) m = fmaxf(m, nf[(size_t)ssrc[e] * D + lane]);
    float r = m - xd;
    agg[(size_t)n * D + lane] = (r >= CLAMP_V) ? r : 0.0f;
}

// ---------- pass 5: MFMA MLP; agg staged in d_out, overwritten in place ----
// One wave per 16-node tile. W held entirely in 64 VGPRs/lane as B-frags.
// A-frags loaded straight from global (L2/IF$-resident rows), no LDS.
__global__ __launch_bounds__(256) void node_mlp_mfma(
        const float* __restrict__ nf,
        float* agg_out,
        const float* __restrict__ W,
        const float* __restrict__ bias,
        int nTiles, int nN) {
    int lane = threadIdx.x & 63;
    int quad = lane >> 4;     // 0..3
    int l16  = lane & 15;
    int waveGlobal = blockIdx.x * 4 + (threadIdx.x >> 6);
    int nWaves = gridDim.x * 4;

    // B-frag: lane holds B[k = ks*32 + quad*8 + j][n = c*16 + l16], j=0..7
    bf16x8 bfrag[4][4];
    #pragma unroll
    for (int c = 0; c < 4; ++c)
        #pragma unroll
        for (int ks = 0; ks < 4; ++ks)
            #pragma unroll
            for (int j = 0; j < 8; ++j) {
                int k = ks * 32 + quad * 8 + j;
                bfrag[c][ks][j] = (__bf16)W[k * D + c * 16 + l16];
            }
    float bv[4];
    #pragma unroll
    for (int c = 0; c < 4; ++c) bv[c] = bias[c * 16 + l16];

    for (int t = waveGlobal; t < nTiles; t += nWaves) {
        int n0 = t * 16;
        int rowA = n0 + l16;
        if (rowA >= nN) rowA = nN - 1;          // clamp for safe loads
        const float* nfr = nf + (size_t)rowA * D;
        const float* agr = agg_out + (size_t)rowA * D;

        floatx4 acc[4] = {{0,0,0,0},{0,0,0,0},{0,0,0,0},{0,0,0,0}};
        #pragma unroll
        for (int ks = 0; ks < 4; ++ks) {
            // A-frag: H[row][k], k = ks*32 + quad*8 + j ; H = [nf | agg]
            const float* p = (ks < 2) ? (nfr + ks * 32 + quad * 8)
                                      : (agr + (ks - 2) * 32 + quad * 8);
            float4 lo = *(const float4*)p;
            float4 hi = *(const float4*)(p + 4);
            bf16x8 a;
            a[0] = (__bf16)lo.x; a[1] = (__bf16)lo.y;
            a[2] = (__bf16)lo.z; a[3] = (__bf16)lo.w;
            a[4] = (__bf16)hi.x; a[5] = (__bf16)hi.y;
            a[6] = (__bf16)hi.z; a[7] = (__bf16)hi.w;
            #pragma unroll
            for (int c = 0; c < 4; ++c)
                acc[c] = __builtin_amdgcn_mfma_f32_16x16x32_bf16(
                             a, bfrag[c][ks], acc[c], 0, 0, 0);
        }
        // C/D: col = c*16 + l16, row = n0 + quad*4 + r
        #pragma unroll
        for (int r = 0; r < 4; ++r) {
            int row = n0 + quad * 4 + r;
            if (row < nN) {
                #pragma unroll
                for (int c = 0; c < 4; ++c) {
                    float v = acc[c][r] + bv[c];
                    agg_out[(size_t)row * D + c * 16 + l16] = fmaxf(v, 0.0f);
                }
            }
        }
    }
}

extern "C" void kernel_launch(void* const* d_in, const int* in_sizes, int n_in,
                              void* d_out, int out_size, void* d_ws, size_t ws_size,
                              hipStream_t stream) {
    const float* nf  = (const float*)d_in[0];
    const int*   src = (const int*)d_in[1];
    const int*   dst = (const int*)d_in[2];
    const float* W   = (const float*)d_in[3];
    const float* b   = (const float*)d_in[4];
    float* out = (float*)d_out;

    int nN = in_sizes[0] / D;
    int nE = in_sizes[1];
    int nTot = nN + 1;
    int nb = (nTot + 4095) / 4096;

    size_t hAlign = ((size_t)nTot * 4 + 255) & ~(size_t)255;
    char* wsb = (char*)d_ws;
    unsigned* hist     = (unsigned*)wsb;
    unsigned* cursor   = (unsigned*)(wsb + hAlign);
    unsigned* partials = (unsigned*)(wsb + 2 * hAlign);
    int*      ssrc     = (int*)(wsb + 2 * hAlign + 4096);

    hipMemsetAsync(hist, 0, (size_t)nTot * 4, stream);

    int gE = (nE + 255) / 256;
    hist_kernel<<<gE, 256, 0, stream>>>(dst, hist, nE);
    scan_partials<<<nb, 256, 0, stream>>>(hist, partials, nTot);
    scan_write<<<nb, 256, 0, stream>>>(hist, partials, cursor, nTot, nb);
    scatter_kernel<<<gE, 256, 0, stream>>>(src, dst, cursor, ssrc, nE);

    segmax_kernel<<<(nN + 3) / 4, 256, 0, stream>>>(nf, ssrc, cursor, out, nN);

    int nTiles = (nN + 15) / 16;
    node_mlp_mfma<<<768, 256, 0, stream>>>(nf, out, W, b, nTiles, nN);
}

// Round 4
// 358.953 us; speedup vs baseline: 1.3559x; 1.0756x over previous
//
#include <hip/hip_runtime.h>
#include <hip/hip_bf16.h>

#define D 64
#define CLAMP_V -10000.0f
#define BNODES 128          // nodes per bucket (dst >> 7)
#define MAXBUCK 1024        // static LDS bound; runtime nbuck = ceil(nN/128) = 782
#define CHUNK 4096          // edges per block in hist/scatter passes

typedef __bf16 bf16x8 __attribute__((ext_vector_type(8)));
typedef float floatx4 __attribute__((ext_vector_type(4)));

__device__ __forceinline__ unsigned ord_encode(float v) {
    unsigned u = __float_as_uint(v);
    return (u & 0x80000000u) ? ~u : (u | 0x80000000u);
}
__device__ __forceinline__ float ord_decode(unsigned o) {
    unsigned u = (o & 0x80000000u) ? (o ^ 0x80000000u) : ~o;
    return __uint_as_float(u);
}

// ---------- pass A: bucket histogram (LDS-privatized) ----------
__global__ __launch_bounds__(256) void hist_bucket(
        const int* __restrict__ dst, unsigned* __restrict__ ghist,
        int nE, int nbuck) {
    __shared__ unsigned h[MAXBUCK];
    int t = threadIdx.x;
    for (int i = t; i < nbuck; i += 256) h[i] = 0;
    __syncthreads();
    int e0 = blockIdx.x * CHUNK;
    for (int i = t; i < CHUNK; i += 256) {
        int e = e0 + i;
        if (e < nE) atomicAdd(&h[dst[e] >> 7], 1u);
    }
    __syncthreads();
    for (int i = t; i < nbuck; i += 256)
        if (h[i]) atomicAdd(&ghist[i], h[i]);
}

// ---------- pass B: exclusive scan over nbuck (single block) ----------
__global__ __launch_bounds__(256) void scan_buckets(
        const unsigned* __restrict__ ghist, unsigned* __restrict__ base,
        unsigned* __restrict__ cursor, int nbuck) {
    __shared__ unsigned ts[256];
    int t = threadIdx.x;
    unsigned v[4], s = 0;
    #pragma unroll
    for (int j = 0; j < 4; ++j) {
        int idx = 4 * t + j;
        v[j] = (idx < nbuck) ? ghist[idx] : 0u;
        s += v[j];
    }
    ts[t] = s; __syncthreads();
    for (int off = 1; off < 256; off <<= 1) {
        unsigned x = (t >= off) ? ts[t - off] : 0u;
        __syncthreads();
        ts[t] += x;
        __syncthreads();
    }
    unsigned run = ts[t] - s;
    #pragma unroll
    for (int j = 0; j < 4; ++j) {
        int idx = 4 * t + j;
        if (idx < nbuck) { base[idx] = run; cursor[idx] = run; }
        run += v[j];
    }
    if (t == 255) base[nbuck] = run;   // total = nE
}

// ---------- pass C: bin edges into buckets, coalesced flush ----------
// payload = (dst&127)<<17 | src  (src < 2^17)
__global__ __launch_bounds__(256) void bucket_scatter(
        const int* __restrict__ src, const int* __restrict__ dst,
        unsigned* __restrict__ cursor, unsigned* __restrict__ packed,
        int nE, int nbuck) {
    __shared__ unsigned cnt[MAXBUCK];
    __shared__ unsigned lbase[MAXBUCK];
    __shared__ unsigned gbase[MAXBUCK];
    __shared__ unsigned off[MAXBUCK];
    __shared__ unsigned payload[CHUNK];
    __shared__ unsigned ts[256];
    int t = threadIdx.x;
    int e0 = blockIdx.x * CHUNK;

    for (int i = t; i < nbuck; i += 256) { cnt[i] = 0; off[i] = 0; }
    __syncthreads();
    // phase 1: count
    for (int i = t; i < CHUNK; i += 256) {
        int e = e0 + i;
        if (e < nE) atomicAdd(&cnt[dst[e] >> 7], 1u);
    }
    __syncthreads();
    // phase 2: block scan of cnt -> lbase
    unsigned v[4], s = 0;
    #pragma unroll
    for (int j = 0; j < 4; ++j) {
        int idx = 4 * t + j;
        v[j] = (idx < nbuck) ? cnt[idx] : 0u;
        s += v[j];
    }
    ts[t] = s; __syncthreads();
    for (int o = 1; o < 256; o <<= 1) {
        unsigned x = (t >= o) ? ts[t - o] : 0u;
        __syncthreads();
        ts[t] += x;
        __syncthreads();
    }
    unsigned run = ts[t] - s;
    #pragma unroll
    for (int j = 0; j < 4; ++j) {
        int idx = 4 * t + j;
        if (idx < nbuck) lbase[idx] = run;
        run += v[j];
    }
    __syncthreads();
    // phase 2b: reserve global ranges (one atomic per nonzero bucket)
    for (int i = t; i < nbuck; i += 256)
        gbase[i] = cnt[i] ? atomicAdd(&cursor[i], cnt[i]) : 0u;
    __syncthreads();
    // phase 3: bin payload into LDS (edges re-read, L2-hot)
    for (int i = t; i < CHUNK; i += 256) {
        int e = e0 + i;
        if (e < nE) {
            int d = dst[e];
            int b = d >> 7;
            unsigned p = atomicAdd(&off[b], 1u);
            payload[lbase[b] + p] = ((unsigned)(d & 127) << 17) | (unsigned)src[e];
        }
    }
    __syncthreads();
    // phase 4: flush runs, lane-contiguous -> line-coalesced global writes
    int wv = t >> 6, ln = t & 63;
    for (int b = wv; b < nbuck; b += 4) {
        unsigned c = cnt[b], lb = lbase[b], gb = gbase[b];
        for (unsigned j = ln; j < c; j += 64)
            packed[gb + j] = payload[lb + j];
    }
}

// ---------- pass D: per-bucket segmax via LDS atomicMax ----------
__global__ __launch_bounds__(256) void bucket_segmax(
        const float* __restrict__ nf, const unsigned* __restrict__ packed,
        const unsigned* __restrict__ base, float* __restrict__ agg, int nN) {
    __shared__ unsigned aggU[BNODES * D];   // 32 KB, ord-encoded
    int b = blockIdx.x;
    int t = threadIdx.x;
    int wv = t >> 6, ln = t & 63;
    for (int i = t; i < BNODES * D; i += 256) aggU[i] = 0;  // decodes to NaN
    __syncthreads();

    unsigned beg = base[b], end = base[b + 1];
    for (unsigned eb = beg + (unsigned)wv * 64; eb < end; eb += 256) {
        unsigned myE = eb + (unsigned)ln;
        unsigned pk = (myE < end) ? packed[myE] : 0u;
        if (eb + 64 <= end) {
            #pragma unroll 8
            for (int j = 0; j < 64; ++j) {
                unsigned pj = __shfl(pk, j);
                int srcN = (int)(pj & 0x1FFFFu);
                int dL   = (int)(pj >> 17);
                float vv = nf[(size_t)srcN * D + ln];
                atomicMax(&aggU[dL * D + ln], ord_encode(vv));
            }
        } else {
            int cnt = (int)(end - eb);
            for (int j = 0; j < cnt; ++j) {
                unsigned pj = __shfl(pk, j);
                int srcN = (int)(pj & 0x1FFFFu);
                int dL   = (int)(pj >> 17);
                float vv = nf[(size_t)srcN * D + ln];
                atomicMax(&aggU[dL * D + ln], ord_encode(vv));
            }
        }
    }
    __syncthreads();
    int n0 = b * BNODES;
    for (int i = wv; i < BNODES; i += 4) {
        int n = n0 + i;
        if (n < nN) {
            float m = ord_decode(aggU[i * D + ln]);
            float r = m - nf[(size_t)n * D + ln];   // max(v) - x == max(v - x)
            agg[(size_t)n * D + ln] = (r >= CLAMP_V) ? r : 0.0f;  // NaN/-inf -> 0
        }
    }
}

// ---------- pass E: MFMA MLP; agg staged in d_out, overwritten in place ----
__global__ __launch_bounds__(256) void node_mlp_mfma(
        const float* __restrict__ nf,
        float* agg_out,
        const float* __restrict__ W,
        const float* __restrict__ bias,
        int nTiles, int nN) {
    int lane = threadIdx.x & 63;
    int quad = lane >> 4;
    int l16  = lane & 15;
    int waveGlobal = blockIdx.x * 4 + (threadIdx.x >> 6);
    int nWaves = gridDim.x * 4;

    bf16x8 bfrag[4][4];
    #pragma unroll
    for (int c = 0; c < 4; ++c)
        #pragma unroll
        for (int ks = 0; ks < 4; ++ks)
            #pragma unroll
            for (int j = 0; j < 8; ++j) {
                int k = ks * 32 + quad * 8 + j;
                bfrag[c][ks][j] = (__bf16)W[k * D + c * 16 + l16];
            }
    float bv[4];
    #pragma unroll
    for (int c = 0; c < 4; ++c) bv[c] = bias[c * 16 + l16];

    for (int t = waveGlobal; t < nTiles; t += nWaves) {
        int n0 = t * 16;
        int rowA = n0 + l16;
        if (rowA >= nN) rowA = nN - 1;
        const float* nfr = nf + (size_t)rowA * D;
        const float* agr = agg_out + (size_t)rowA * D;

        floatx4 acc[4] = {{0,0,0,0},{0,0,0,0},{0,0,0,0},{0,0,0,0}};
        #pragma unroll
        for (int ks = 0; ks < 4; ++ks) {
            const float* p = (ks < 2) ? (nfr + ks * 32 + quad * 8)
                                      : (agr + (ks - 2) * 32 + quad * 8);
            float4 lo = *(const float4*)p;
            float4 hi = *(const float4*)(p + 4);
            bf16x8 a;
            a[0] = (__bf16)lo.x; a[1] = (__bf16)lo.y;
            a[2] = (__bf16)lo.z; a[3] = (__bf16)lo.w;
            a[4] = (__bf16)hi.x; a[5] = (__bf16)hi.y;
            a[6] = (__bf16)hi.z; a[7] = (__bf16)hi.w;
            #pragma unroll
            for (int c = 0; c < 4; ++c)
                acc[c] = __builtin_amdgcn_mfma_f32_16x16x32_bf16(
                             a, bfrag[c][ks], acc[c], 0, 0, 0);
        }
        #pragma unroll
        for (int r = 0; r < 4; ++r) {
            int row = n0 + quad * 4 + r;
            if (row < nN) {
                #pragma unroll
                for (int c = 0; c < 4; ++c) {
                    float vv = acc[c][r] + bv[c];
                    agg_out[(size_t)row * D + c * 16 + l16] = fmaxf(vv, 0.0f);
                }
            }
        }
    }
}

extern "C" void kernel_launch(void* const* d_in, const int* in_sizes, int n_in,
                              void* d_out, int out_size, void* d_ws, size_t ws_size,
                              hipStream_t stream) {
    const float* nf  = (const float*)d_in[0];
    const int*   src = (const int*)d_in[1];
    const int*   dst = (const int*)d_in[2];
    const float* W   = (const float*)d_in[3];
    const float* b   = (const float*)d_in[4];
    float* out = (float*)d_out;

    int nN = in_sizes[0] / D;
    int nE = in_sizes[1];
    int nbuck = (nN + BNODES - 1) / BNODES;     // 782

    // ws layout
    char* wsb = (char*)d_ws;
    unsigned* ghist  = (unsigned*)wsb;                       // MAXBUCK
    unsigned* base   = (unsigned*)(wsb + 4 * MAXBUCK);       // MAXBUCK+1
    unsigned* cursor = (unsigned*)(wsb + 4 * MAXBUCK + 4 * (MAXBUCK + 1));
    unsigned* packed = (unsigned*)(wsb + 16384 + 3 * 4 * MAXBUCK); // nE entries

    hipMemsetAsync(ghist, 0, (size_t)nbuck * 4, stream);

    int nbE = (nE + CHUNK - 1) / CHUNK;        // 391
    hist_bucket<<<nbE, 256, 0, stream>>>(dst, ghist, nE, nbuck);
    scan_buckets<<<1, 256, 0, stream>>>(ghist, base, cursor, nbuck);
    bucket_scatter<<<nbE, 256, 0, stream>>>(src, dst, cursor, packed, nE, nbuck);
    bucket_segmax<<<nbuck, 256, 0, stream>>>(nf, packed, base, out, nN);

    int nTiles = (nN + 15) / 16;
    node_mlp_mfma<<<768, 256, 0, stream>>>(nf, out, W, b, nTiles, nN);
}

// Round 5
// 328.136 us; speedup vs baseline: 1.4832x; 1.0939x over previous
//
#include <hip/hip_runtime.h>
#include <hip/hip_bf16.h>

#define D 64
#define CLAMP_V -10000.0f
#define BNODES 64           // nodes per bucket (dst >> 6)
#define BSHIFT 6
#define MAXBUCK 2048        // static bound; runtime nbuck = ceil(100k/64) = 1563
#define CHUNK 4096          // edges per block in hist/scatter passes

typedef __bf16 bf16x4 __attribute__((ext_vector_type(4)));
typedef __bf16 bf16x8 __attribute__((ext_vector_type(8)));
typedef float floatx4 __attribute__((ext_vector_type(4)));

__device__ __forceinline__ unsigned ord_encode_bits(unsigned u) {
    return (u & 0x80000000u) ? ~u : (u | 0x80000000u);
}
__device__ __forceinline__ float ord_decode(unsigned o) {
    unsigned u = (o & 0x80000000u) ? (o ^ 0x80000000u) : ~o;
    return __uint_as_float(u);
}

// ---------- pass 0: fp32 -> bf16 copy of node features ----------
__global__ __launch_bounds__(256) void tobf16_kernel(
        const float* __restrict__ nf, __bf16* __restrict__ nf16, int n4) {
    int i = blockIdx.x * blockDim.x + threadIdx.x;
    if (i < n4) {
        float4 v = ((const float4*)nf)[i];
        bf16x4 o = { (__bf16)v.x, (__bf16)v.y, (__bf16)v.z, (__bf16)v.w };
        ((bf16x4*)nf16)[i] = o;
    }
}

// ---------- pass A: bucket histogram (LDS-privatized) ----------
__global__ __launch_bounds__(256) void hist_bucket(
        const int* __restrict__ dst, unsigned* __restrict__ ghist,
        int nE, int nbuck) {
    __shared__ unsigned h[MAXBUCK];
    int t = threadIdx.x;
    for (int i = t; i < nbuck; i += 256) h[i] = 0;
    __syncthreads();
    int e0 = blockIdx.x * CHUNK;
    for (int i = t; i < CHUNK; i += 256) {
        int e = e0 + i;
        if (e < nE) atomicAdd(&h[dst[e] >> BSHIFT], 1u);
    }
    __syncthreads();
    for (int i = t; i < nbuck; i += 256)
        if (h[i]) atomicAdd(&ghist[i], h[i]);
}

// ---------- pass B: exclusive scan over nbuck (single block) ----------
__global__ __launch_bounds__(256) void scan_buckets(
        const unsigned* __restrict__ ghist, unsigned* __restrict__ base,
        unsigned* __restrict__ cursor, int nbuck) {
    __shared__ unsigned ts[256];
    int t = threadIdx.x;
    unsigned v[8], s = 0;
    #pragma unroll
    for (int j = 0; j < 8; ++j) {
        int idx = 8 * t + j;
        v[j] = (idx < nbuck) ? ghist[idx] : 0u;
        s += v[j];
    }
    ts[t] = s; __syncthreads();
    for (int off = 1; off < 256; off <<= 1) {
        unsigned x = (t >= off) ? ts[t - off] : 0u;
        __syncthreads();
        ts[t] += x;
        __syncthreads();
    }
    unsigned run = ts[t] - s;
    #pragma unroll
    for (int j = 0; j < 8; ++j) {
        int idx = 8 * t + j;
        if (idx < nbuck) { base[idx] = run; cursor[idx] = run; }
        run += v[j];
    }
    if (t == 255) base[nbuck] = run;   // total = nE
}

// ---------- pass C: bin edges into buckets, coalesced flush ----------
// payload = (dst&63)<<17 | src  (src < 2^17)
__global__ __launch_bounds__(256) void bucket_scatter(
        const int* __restrict__ src, const int* __restrict__ dst,
        unsigned* __restrict__ cursor, unsigned* __restrict__ packed,
        int nE, int nbuck) {
    __shared__ unsigned cnt[MAXBUCK];
    __shared__ unsigned lbase[MAXBUCK];
    __shared__ unsigned gbase[MAXBUCK];
    __shared__ unsigned off[MAXBUCK];
    __shared__ unsigned payload[CHUNK];
    __shared__ unsigned ts[256];
    int t = threadIdx.x;
    int e0 = blockIdx.x * CHUNK;

    for (int i = t; i < nbuck; i += 256) { cnt[i] = 0; off[i] = 0; }
    __syncthreads();
    for (int i = t; i < CHUNK; i += 256) {
        int e = e0 + i;
        if (e < nE) atomicAdd(&cnt[dst[e] >> BSHIFT], 1u);
    }
    __syncthreads();
    unsigned v[8], s = 0;
    #pragma unroll
    for (int j = 0; j < 8; ++j) {
        int idx = 8 * t + j;
        v[j] = (idx < nbuck) ? cnt[idx] : 0u;
        s += v[j];
    }
    ts[t] = s; __syncthreads();
    for (int o = 1; o < 256; o <<= 1) {
        unsigned x = (t >= o) ? ts[t - o] : 0u;
        __syncthreads();
        ts[t] += x;
        __syncthreads();
    }
    unsigned run = ts[t] - s;
    #pragma unroll
    for (int j = 0; j < 8; ++j) {
        int idx = 8 * t + j;
        if (idx < nbuck) lbase[idx] = run;
        run += v[j];
    }
    __syncthreads();
    for (int i = t; i < nbuck; i += 256)
        gbase[i] = cnt[i] ? atomicAdd(&cursor[i], cnt[i]) : 0u;
    __syncthreads();
    for (int i = t; i < CHUNK; i += 256) {
        int e = e0 + i;
        if (e < nE) {
            int d = dst[e];
            int b = d >> BSHIFT;
            unsigned p = atomicAdd(&off[b], 1u);
            payload[lbase[b] + p] = ((unsigned)(d & (BNODES - 1)) << 17) | (unsigned)src[e];
        }
    }
    __syncthreads();
    int wv = t >> 6, ln = t & 63;
    for (int b = wv; b < nbuck; b += 4) {
        unsigned c = cnt[b], lb = lbase[b], gb = gbase[b];
        for (unsigned j = ln; j < c; j += 64)
            packed[gb + j] = payload[lb + j];
    }
}

// ---------- pass D: per-bucket segmax, bf16 gathers, LDS atomicMax ----------
__global__ __launch_bounds__(256) void bucket_segmax(
        const ushort* __restrict__ nf16, const unsigned* __restrict__ packed,
        const unsigned* __restrict__ base, float* __restrict__ agg, int nN) {
    __shared__ unsigned aggU[BNODES * D];   // 16 KB, ord-encoded fp32
    int b = blockIdx.x;
    int t = threadIdx.x;
    int wv = t >> 6, ln = t & 63;
    for (int i = t; i < BNODES * D; i += 256) aggU[i] = 0;  // decodes to -NaN
    __syncthreads();

    unsigned beg = base[b], end = base[b + 1];
    for (unsigned eb = beg + (unsigned)wv * 64; eb < end; eb += 256) {
        unsigned myE = eb + (unsigned)ln;
        unsigned pk = (myE < end) ? packed[myE] : 0u;
        if (eb + 64 <= end) {
            #pragma unroll 8
            for (int j = 0; j < 64; ++j) {
                unsigned pj = __shfl(pk, j);
                int srcN = (int)(pj & 0x1FFFFu);
                int dL   = (int)(pj >> 17);
                unsigned u = (unsigned)nf16[(size_t)srcN * D + ln] << 16;
                atomicMax(&aggU[dL * D + ln], ord_encode_bits(u));
            }
        } else {
            int cnt = (int)(end - eb);
            for (int j = 0; j < cnt; ++j) {
                unsigned pj = __shfl(pk, j);
                int srcN = (int)(pj & 0x1FFFFu);
                int dL   = (int)(pj >> 17);
                unsigned u = (unsigned)nf16[(size_t)srcN * D + ln] << 16;
                atomicMax(&aggU[dL * D + ln], ord_encode_bits(u));
            }
        }
    }
    __syncthreads();
    int n0 = b * BNODES;
    for (int i = wv; i < BNODES; i += 4) {
        int n = n0 + i;
        if (n < nN) {
            float m = ord_decode(aggU[i * D + ln]);
            float x = __uint_as_float((unsigned)nf16[(size_t)n * D + ln] << 16);
            float r = m - x;                         // max(v) - x == max(v - x)
            agg[(size_t)n * D + ln] = (r >= CLAMP_V) ? r : 0.0f;  // NaN -> 0
        }
    }
}

// ---------- pass E: MFMA MLP; agg staged in d_out, overwritten in place ----
__global__ __launch_bounds__(256) void node_mlp_mfma(
        const __bf16* __restrict__ nf16,
        float* agg_out,
        const float* __restrict__ W,
        const float* __restrict__ bias,
        int nTiles, int nN) {
    int lane = threadIdx.x & 63;
    int quad = lane >> 4;
    int l16  = lane & 15;
    int waveGlobal = blockIdx.x * 4 + (threadIdx.x >> 6);
    int nWaves = gridDim.x * 4;

    bf16x8 bfrag[4][4];
    #pragma unroll
    for (int c = 0; c < 4; ++c)
        #pragma unroll
        for (int ks = 0; ks < 4; ++ks)
            #pragma unroll
            for (int j = 0; j < 8; ++j) {
                int k = ks * 32 + quad * 8 + j;
                bfrag[c][ks][j] = (__bf16)W[k * D + c * 16 + l16];
            }
    float bv[4];
    #pragma unroll
    for (int c = 0; c < 4; ++c) bv[c] = bias[c * 16 + l16];

    for (int t = waveGlobal; t < nTiles; t += nWaves) {
        int n0 = t * 16;
        int rowA = n0 + l16;
        if (rowA >= nN) rowA = nN - 1;
        const __bf16* nfr = nf16 + (size_t)rowA * D;
        const float*  agr = agg_out + (size_t)rowA * D;

        floatx4 acc[4] = {{0,0,0,0},{0,0,0,0},{0,0,0,0},{0,0,0,0}};
        #pragma unroll
        for (int ks = 0; ks < 2; ++ks) {
            // nf half: direct bf16 16B load, no conversion
            bf16x8 a = *(const bf16x8*)(nfr + ks * 32 + quad * 8);
            #pragma unroll
            for (int c = 0; c < 4; ++c)
                acc[c] = __builtin_amdgcn_mfma_f32_16x16x32_bf16(
                             a, bfrag[c][ks], acc[c], 0, 0, 0);
        }
        #pragma unroll
        for (int ks = 2; ks < 4; ++ks) {
            const float* p = agr + (ks - 2) * 32 + quad * 8;
            float4 lo = *(const float4*)p;
            float4 hi = *(const float4*)(p + 4);
            bf16x8 a;
            a[0] = (__bf16)lo.x; a[1] = (__bf16)lo.y;
            a[2] = (__bf16)lo.z; a[3] = (__bf16)lo.w;
            a[4] = (__bf16)hi.x; a[5] = (__bf16)hi.y;
            a[6] = (__bf16)hi.z; a[7] = (__bf16)hi.w;
            #pragma unroll
            for (int c = 0; c < 4; ++c)
                acc[c] = __builtin_amdgcn_mfma_f32_16x16x32_bf16(
                             a, bfrag[c][ks], acc[c], 0, 0, 0);
        }
        #pragma unroll
        for (int r = 0; r < 4; ++r) {
            int row = n0 + quad * 4 + r;
            if (row < nN) {
                #pragma unroll
                for (int c = 0; c < 4; ++c) {
                    float vv = acc[c][r] + bv[c];
                    agg_out[(size_t)row * D + c * 16 + l16] = fmaxf(vv, 0.0f);
                }
            }
        }
    }
}

extern "C" void kernel_launch(void* const* d_in, const int* in_sizes, int n_in,
                              void* d_out, int out_size, void* d_ws, size_t ws_size,
                              hipStream_t stream) {
    const float* nf  = (const float*)d_in[0];
    const int*   src = (const int*)d_in[1];
    const int*   dst = (const int*)d_in[2];
    const float* W   = (const float*)d_in[3];
    const float* b   = (const float*)d_in[4];
    float* out = (float*)d_out;

    int nN = in_sizes[0] / D;
    int nE = in_sizes[1];
    int nbuck = (nN + BNODES - 1) / BNODES;     // 1563

    // ws layout
    char* wsb = (char*)d_ws;
    size_t nf16B = (((size_t)nN * D * 2) + 255) & ~(size_t)255;
    __bf16*   nf16   = (__bf16*)wsb;
    unsigned* ghist  = (unsigned*)(wsb + nf16B);
    unsigned* base   = (unsigned*)(wsb + nf16B + 4 * MAXBUCK);
    unsigned* cursor = (unsigned*)(wsb + nf16B + 4 * MAXBUCK + 4 * (MAXBUCK + 2));
    unsigned* packed = (unsigned*)(wsb + nf16B + 4 * MAXBUCK + 8 * (MAXBUCK + 2));

    hipMemsetAsync(ghist, 0, (size_t)nbuck * 4, stream);

    int n4 = nN * D / 4;
    tobf16_kernel<<<(n4 + 255) / 256, 256, 0, stream>>>(nf, nf16, n4);

    int nbE = (nE + CHUNK - 1) / CHUNK;        // 391
    hist_bucket<<<nbE, 256, 0, stream>>>(dst, ghist, nE, nbuck);
    scan_buckets<<<1, 256, 0, stream>>>(ghist, base, cursor, nbuck);
    bucket_scatter<<<nbE, 256, 0, stream>>>(src, dst, cursor, packed, nE, nbuck);
    bucket_segmax<<<nbuck, 256, 0, stream>>>((const ushort*)nf16, packed, base, out, nN);

    int nTiles = (nN + 15) / 16;
    node_mlp_mfma<<<768, 256, 0, stream>>>(nf16, out, W, b, nTiles, nN);
}

// Round 6
// 234.639 us; speedup vs baseline: 2.0742x; 1.3985x over previous
//
#include <hip/hip_runtime.h>
#include <hip/hip_bf16.h>

#define D 64
#define CLAMP_V -10000.0f
#define BNODES 64           // nodes per bucket (dst >> 6)
#define BSHIFT 6
#define MAXBUCK 2048        // static bound; runtime nbuck = ceil(100k/64) = 1563
#define CHUNK 4096          // edges per block in hist/scatter passes
#define SWEEP 2048          // segmax LDS sort capacity per sweep

typedef __bf16 bf16x4 __attribute__((ext_vector_type(4)));
typedef __bf16 bf16x8 __attribute__((ext_vector_type(8)));
typedef float floatx4 __attribute__((ext_vector_type(4)));
typedef unsigned short u16x2 __attribute__((ext_vector_type(2)));
typedef short s16x2 __attribute__((ext_vector_type(2)));

// packed max of 2x u16 (v_pk_max_u16)
__device__ __forceinline__ unsigned pkmax(unsigned a, unsigned b) {
    u16x2 r = __builtin_elementwise_max(__builtin_bit_cast(u16x2, a),
                                        __builtin_bit_cast(u16x2, b));
    return __builtin_bit_cast(unsigned, r);
}
// packed ord-encode of 2x bf16 (monotone u16): pos -> |0x8000, neg -> ~
__device__ __forceinline__ unsigned pk_ord_encode(unsigned g) {
    s16x2 t = __builtin_bit_cast(s16x2, g) >> 15;              // -1 per neg half
    unsigned m = __builtin_bit_cast(unsigned, t) & 0x7FFF7FFFu;
    return g ^ (m | 0x80008000u);
}
// packed ord-decode (top bit set => was positive)
__device__ __forceinline__ unsigned pk_ord_decode(unsigned e) {
    s16x2 t = __builtin_bit_cast(s16x2, e) >> 15;              // -1 per "positive"
    unsigned m = (~__builtin_bit_cast(unsigned, t)) & 0x7FFF7FFFu;
    return e ^ (m | 0x80008000u);
}

// ---------- pass 0: fp32 -> bf16 copy of node features ----------
__global__ __launch_bounds__(256) void tobf16_kernel(
        const float* __restrict__ nf, __bf16* __restrict__ nf16, int n4) {
    int i = blockIdx.x * blockDim.x + threadIdx.x;
    if (i < n4) {
        float4 v = ((const float4*)nf)[i];
        bf16x4 o = { (__bf16)v.x, (__bf16)v.y, (__bf16)v.z, (__bf16)v.w };
        ((bf16x4*)nf16)[i] = o;
    }
}

// ---------- pass A: bucket histogram (LDS-privatized) ----------
__global__ __launch_bounds__(256) void hist_bucket(
        const int* __restrict__ dst, unsigned* __restrict__ ghist,
        int nE, int nbuck) {
    __shared__ unsigned h[MAXBUCK];
    int t = threadIdx.x;
    for (int i = t; i < nbuck; i += 256) h[i] = 0;
    __syncthreads();
    int e0 = blockIdx.x * CHUNK;
    for (int i = t; i < CHUNK; i += 256) {
        int e = e0 + i;
        if (e < nE) atomicAdd(&h[dst[e] >> BSHIFT], 1u);
    }
    __syncthreads();
    for (int i = t; i < nbuck; i += 256)
        if (h[i]) atomicAdd(&ghist[i], h[i]);
}

// ---------- pass B: exclusive scan over nbuck (single block) ----------
__global__ __launch_bounds__(256) void scan_buckets(
        const unsigned* __restrict__ ghist, unsigned* __restrict__ base,
        unsigned* __restrict__ cursor, int nbuck) {
    __shared__ unsigned ts[256];
    int t = threadIdx.x;
    unsigned v[8], s = 0;
    #pragma unroll
    for (int j = 0; j < 8; ++j) {
        int idx = 8 * t + j;
        v[j] = (idx < nbuck) ? ghist[idx] : 0u;
        s += v[j];
    }
    ts[t] = s; __syncthreads();
    for (int off = 1; off < 256; off <<= 1) {
        unsigned x = (t >= off) ? ts[t - off] : 0u;
        __syncthreads();
        ts[t] += x;
        __syncthreads();
    }
    unsigned run = ts[t] - s;
    #pragma unroll
    for (int j = 0; j < 8; ++j) {
        int idx = 8 * t + j;
        if (idx < nbuck) { base[idx] = run; cursor[idx] = run; }
        run += v[j];
    }
    if (t == 255) base[nbuck] = run;   // total = nE
}

// ---------- pass C: bin edges into buckets, flattened coalesced flush ------
// payload = (dst&63)<<17 | src  (src < 2^17)
__global__ __launch_bounds__(256) void bucket_scatter(
        const int* __restrict__ src, const int* __restrict__ dst,
        unsigned* __restrict__ cursor, unsigned* __restrict__ packed,
        int nE, int nbuck) {
    __shared__ unsigned cnt[MAXBUCK];
    __shared__ unsigned lbase[MAXBUCK];
    __shared__ unsigned gbase[MAXBUCK];
    __shared__ unsigned off[MAXBUCK];
    __shared__ unsigned payload[CHUNK];
    __shared__ unsigned short bid[CHUNK];
    __shared__ unsigned ts[256];
    int t = threadIdx.x;
    int e0 = blockIdx.x * CHUNK;
    int eCnt = nE - e0; if (eCnt > CHUNK) eCnt = CHUNK;

    for (int i = t; i < nbuck; i += 256) { cnt[i] = 0; off[i] = 0; }
    __syncthreads();
    for (int i = t; i < eCnt; i += 256)
        atomicAdd(&cnt[dst[e0 + i] >> BSHIFT], 1u);
    __syncthreads();
    unsigned v[8], s = 0;
    #pragma unroll
    for (int j = 0; j < 8; ++j) {
        int idx = 8 * t + j;
        v[j] = (idx < nbuck) ? cnt[idx] : 0u;
        s += v[j];
    }
    ts[t] = s; __syncthreads();
    for (int o = 1; o < 256; o <<= 1) {
        unsigned x = (t >= o) ? ts[t - o] : 0u;
        __syncthreads();
        ts[t] += x;
        __syncthreads();
    }
    unsigned run = ts[t] - s;
    #pragma unroll
    for (int j = 0; j < 8; ++j) {
        int idx = 8 * t + j;
        if (idx < nbuck) lbase[idx] = run;
        run += v[j];
    }
    __syncthreads();
    for (int i = t; i < nbuck; i += 256)
        gbase[i] = cnt[i] ? atomicAdd(&cursor[i], cnt[i]) : 0u;
    __syncthreads();
    for (int i = t; i < eCnt; i += 256) {
        int e = e0 + i;
        int d = dst[e];
        int b = d >> BSHIFT;
        unsigned p = atomicAdd(&off[b], 1u);
        unsigned pos = lbase[b] + p;
        payload[pos] = ((unsigned)(d & (BNODES - 1)) << 17) | (unsigned)src[e];
        bid[pos] = (unsigned short)b;
    }
    __syncthreads();
    // flattened flush: full lane utilization; same-run entries are adjacent
    // lanes -> coalesce into partial-line bursts
    for (int i = t; i < eCnt; i += 256) {
        unsigned b = bid[i];
        packed[gbase[b] + ((unsigned)i - lbase[b])] = payload[i];
    }
}

// ---------- pass D: per-bucket counting sort + register packed max ----------
__global__ __launch_bounds__(256) void bucket_segmax(
        const unsigned* __restrict__ nfu,       // nf16 as dwords, 32/row
        const unsigned* __restrict__ packed,
        const unsigned* __restrict__ base,
        unsigned* __restrict__ agg16u,          // bf16 agg as dwords, 32/row
        int nN) {
    __shared__ unsigned aggS[BNODES * 32];      // packed ord-bf16 max, 8 KB
    __shared__ unsigned sbuf[SWEEP];            // sorted src indices, 8 KB
    __shared__ unsigned rstart[BNODES + 1];
    __shared__ unsigned pos[BNODES];
    int b = blockIdx.x;
    int t = threadIdx.x;
    int wv = t >> 6, ln = t & 63;

    for (int i = t; i < BNODES * 32; i += 256) aggS[i] = 0;  // minimal ord
    unsigned beg = base[b], end = base[b + 1];

    for (unsigned s0 = beg; s0 < end; s0 += SWEEP) {
        unsigned scnt = end - s0; if (scnt > SWEEP) scnt = SWEEP;
        if (t < BNODES) pos[t] = 0;
        __syncthreads();
        for (unsigned i = t; i < scnt; i += 256)
            atomicAdd(&pos[packed[s0 + i] >> 17], 1u);
        __syncthreads();
        if (t == 0) {
            unsigned r = 0;
            for (int k = 0; k < BNODES; ++k) {
                unsigned c = pos[k]; rstart[k] = r; pos[k] = r; r += c;
            }
            rstart[BNODES] = r;
        }
        __syncthreads();
        for (unsigned i = t; i < scnt; i += 256) {
            unsigned e = packed[s0 + i];
            unsigned p = atomicAdd(&pos[e >> 17], 1u);
            sbuf[p] = e & 0x1FFFFu;
        }
        __syncthreads();
        // register max over contiguous runs; 2 edges/iter (half-wave each),
        // 2 dims/lane packed
        int half = ln >> 5, dln = ln & 31;
        for (int node = wv; node < BNODES; node += 4) {
            unsigned rb = rstart[node], re = rstart[node + 1];
            if (rb == re) continue;
            unsigned m = 0;
            for (unsigned j = rb; j < re; j += 2) {
                unsigned jj = j + (unsigned)half;
                if (jj >= re) jj = re - 1;          // dup tail: max idempotent
                unsigned srcN = sbuf[jj];
                unsigned g = nfu[(size_t)srcN * 32 + dln];
                m = pkmax(m, pk_ord_encode(g));
            }
            m = pkmax(m, __shfl_xor(m, 32, 64));    // cross-half merge
            if (ln < 32) {
                unsigned idx = node * 32 + ln;
                aggS[idx] = pkmax(aggS[idx], m);    // wave owns node: plain RMW
            }
        }
        __syncthreads();    // pos/rstart/sbuf reused next sweep
    }
    // epilogue: decode, r = max(v) - x, clamp, store bf16 pair
    int n0 = b * BNODES;
    for (int node = wv; node < BNODES; node += 4) {
        int n = n0 + node;
        if (n < nN && ln < 32) {
            unsigned raw = pk_ord_decode(aggS[node * 32 + ln]); // empty -> NaN
            unsigned xr  = nfu[(size_t)n * 32 + ln];
            float v0 = __uint_as_float(raw << 16);
            float v1 = __uint_as_float(raw & 0xFFFF0000u);
            float x0 = __uint_as_float(xr << 16);
            float x1 = __uint_as_float(xr & 0xFFFF0000u);
            float r0 = v0 - x0; r0 = (r0 >= CLAMP_V) ? r0 : 0.0f;  // NaN -> 0
            float r1 = v1 - x1; r1 = (r1 >= CLAMP_V) ? r1 : 0.0f;
            __bf16 b0 = (__bf16)r0, b1 = (__bf16)r1;
            unsigned o = ((unsigned)__builtin_bit_cast(unsigned short, b1) << 16)
                       |  (unsigned)__builtin_bit_cast(unsigned short, b0);
            agg16u[(size_t)n * 32 + ln] = o;
        }
    }
}

// ---------- pass E: MFMA MLP; all-bf16 A operands ----------
__global__ __launch_bounds__(256) void node_mlp_mfma(
        const __bf16* __restrict__ nf16,
        const __bf16* __restrict__ agg16,
        float* __restrict__ out,
        const float* __restrict__ W,
        const float* __restrict__ bias,
        int nTiles, int nN) {
    int lane = threadIdx.x & 63;
    int quad = lane >> 4;
    int l16  = lane & 15;
    int waveGlobal = blockIdx.x * 4 + (threadIdx.x >> 6);
    int nWaves = gridDim.x * 4;

    bf16x8 bfrag[4][4];
    #pragma unroll
    for (int c = 0; c < 4; ++c)
        #pragma unroll
        for (int ks = 0; ks < 4; ++ks)
            #pragma unroll
            for (int j = 0; j < 8; ++j) {
                int k = ks * 32 + quad * 8 + j;
                bfrag[c][ks][j] = (__bf16)W[k * D + c * 16 + l16];
            }
    float bv[4];
    #pragma unroll
    for (int c = 0; c < 4; ++c) bv[c] = bias[c * 16 + l16];

    for (int t = waveGlobal; t < nTiles; t += nWaves) {
        int n0 = t * 16;
        int rowA = n0 + l16;
        if (rowA >= nN) rowA = nN - 1;
        const __bf16* nfr = nf16  + (size_t)rowA * D;
        const __bf16* agr = agg16 + (size_t)rowA * D;

        floatx4 acc[4] = {{0,0,0,0},{0,0,0,0},{0,0,0,0},{0,0,0,0}};
        #pragma unroll
        for (int ks = 0; ks < 4; ++ks) {
            const __bf16* p = (ks < 2) ? (nfr + ks * 32 + quad * 8)
                                       : (agr + (ks - 2) * 32 + quad * 8);
            bf16x8 a = *(const bf16x8*)p;
            #pragma unroll
            for (int c = 0; c < 4; ++c)
                acc[c] = __builtin_amdgcn_mfma_f32_16x16x32_bf16(
                             a, bfrag[c][ks], acc[c], 0, 0, 0);
        }
        #pragma unroll
        for (int r = 0; r < 4; ++r) {
            int row = n0 + quad * 4 + r;
            if (row < nN) {
                #pragma unroll
                for (int c = 0; c < 4; ++c) {
                    float vv = acc[c][r] + bv[c];
                    out[(size_t)row * D + c * 16 + l16] = fmaxf(vv, 0.0f);
                }
            }
        }
    }
}

extern "C" void kernel_launch(void* const* d_in, const int* in_sizes, int n_in,
                              void* d_out, int out_size, void* d_ws, size_t ws_size,
                              hipStream_t stream) {
    const float* nf  = (const float*)d_in[0];
    const int*   src = (const int*)d_in[1];
    const int*   dst = (const int*)d_in[2];
    const float* W   = (const float*)d_in[3];
    const float* b   = (const float*)d_in[4];
    float* out = (float*)d_out;

    int nN = in_sizes[0] / D;
    int nE = in_sizes[1];
    int nbuck = (nN + BNODES - 1) / BNODES;     // 1563

    // ws layout
    char* wsb = (char*)d_ws;
    size_t nfB  = (((size_t)nN * D * 2) + 255) & ~(size_t)255;  // 12.8 MB
    size_t pkB  = (((size_t)nE * 4)     + 255) & ~(size_t)255;  // 6.4 MB
    __bf16*   nf16   = (__bf16*)wsb;
    __bf16*   agg16  = (__bf16*)(wsb + nfB);
    unsigned* packed = (unsigned*)(wsb + 2 * nfB);
    unsigned* ghist  = (unsigned*)(wsb + 2 * nfB + pkB);
    unsigned* base   = (unsigned*)(wsb + 2 * nfB + pkB + 4 * MAXBUCK);
    unsigned* cursor = (unsigned*)(wsb + 2 * nfB + pkB + 4 * MAXBUCK + 4 * (MAXBUCK + 2));

    hipMemsetAsync(ghist, 0, (size_t)nbuck * 4, stream);

    int n4 = nN * D / 4;
    tobf16_kernel<<<(n4 + 255) / 256, 256, 0, stream>>>(nf, nf16, n4);

    int nbE = (nE + CHUNK - 1) / CHUNK;        // 391
    hist_bucket<<<nbE, 256, 0, stream>>>(dst, ghist, nE, nbuck);
    scan_buckets<<<1, 256, 0, stream>>>(ghist, base, cursor, nbuck);
    bucket_scatter<<<nbE, 256, 0, stream>>>(src, dst, cursor, packed, nE, nbuck);
    bucket_segmax<<<nbuck, 256, 0, stream>>>((const unsigned*)nf16, packed, base,
                                             (unsigned*)agg16, nN);

    int nTiles = (nN + 15) / 16;
    node_mlp_mfma<<<768, 256, 0, stream>>>(nf16, agg16, out, W, b, nTiles, nN);
}

// Round 7
// 231.615 us; speedup vs baseline: 2.1013x; 1.0131x over previous
//
#include <hip/hip_runtime.h>
#include <hip/hip_bf16.h>

#define D 64
#define CLAMP_V -10000.0f
#define BNODES 64           // nodes per bucket (dst >> 6)
#define BSHIFT 6
#define MAXBUCK 2048        // static bound; runtime nbuck = ceil(100k/64) = 1563
#define HCHUNK 4096         // edges per hist slice (inside prep)
#define SCHUNK 2048         // edges per scatter block
#define HN 32               // nodes per segmax block (half bucket)
#define SWIN 1024           // segmax sweep window (entries of bucket range)

typedef __bf16 bf16x4 __attribute__((ext_vector_type(4)));
typedef __bf16 bf16x8 __attribute__((ext_vector_type(8)));
typedef float floatx4 __attribute__((ext_vector_type(4)));
typedef unsigned short u16x2 __attribute__((ext_vector_type(2)));
typedef short s16x2 __attribute__((ext_vector_type(2)));

// packed max of 2x u16 (v_pk_max_u16)
__device__ __forceinline__ unsigned pkmax(unsigned a, unsigned b) {
    u16x2 r = __builtin_elementwise_max(__builtin_bit_cast(u16x2, a),
                                        __builtin_bit_cast(u16x2, b));
    return __builtin_bit_cast(unsigned, r);
}
// packed ord-encode of 2x bf16 (monotone u16): pos -> |0x8000, neg -> ~
__device__ __forceinline__ unsigned pk_ord_encode(unsigned g) {
    s16x2 t = __builtin_bit_cast(s16x2, g) >> 15;
    unsigned m = __builtin_bit_cast(unsigned, t) & 0x7FFF7FFFu;
    return g ^ (m | 0x80008000u);
}
__device__ __forceinline__ unsigned pk_ord_decode(unsigned e) {
    s16x2 t = __builtin_bit_cast(s16x2, e) >> 15;
    unsigned m = (~__builtin_bit_cast(unsigned, t)) & 0x7FFF7FFFu;
    return e ^ (m | 0x80008000u);
}

// ---------- pass 0: fp32->bf16 conversion + dst histogram + W frag layout ---
__global__ __launch_bounds__(256) void prep_kernel(
        const float* __restrict__ nf, __bf16* __restrict__ nf16, int n4,
        const int* __restrict__ dst, unsigned* __restrict__ ghist,
        int nE, int nbuck,
        const float* __restrict__ W, __bf16* __restrict__ wfrag,
        int histBlocks, int wBlock) {
    __shared__ unsigned h[MAXBUCK];
    int blk = blockIdx.x, t = threadIdx.x;
    int i = blk * 256 + t;
    if (i < n4) {
        float4 v = ((const float4*)nf)[i];
        bf16x4 o = { (__bf16)v.x, (__bf16)v.y, (__bf16)v.z, (__bf16)v.w };
        ((bf16x4*)nf16)[i] = o;
    }
    if (blk < histBlocks) {
        for (int k = t; k < nbuck; k += 256) h[k] = 0;
        __syncthreads();
        int e0 = blk * HCHUNK;
        int ec = nE - e0; if (ec > HCHUNK) ec = HCHUNK;
        for (int k = t; k < ec; k += 256) atomicAdd(&h[dst[e0 + k] >> BSHIFT], 1u);
        __syncthreads();
        for (int k = t; k < nbuck; k += 256)
            if (h[k]) atomicAdd(&ghist[k], h[k]);
    }
    if (blk == wBlock) {
        // W[k][n] fp32 -> bf16 in MFMA-fragment order:
        // fidx = ((ks*4+c)*64 + quad*16+l16)*8 + j, k=ks*32+quad*8+j, n=c*16+l16
        for (int idx = t; idx < 2 * D * D; idx += 256) {
            int k = idx >> 6, n = idx & 63;
            int ks = k >> 5, r = k & 31, quad = r >> 3, j = r & 7;
            int c = n >> 4, l16 = n & 15;
            int fidx = (((ks * 4 + c) * 64) + quad * 16 + l16) * 8 + j;
            wfrag[fidx] = (__bf16)W[idx];
        }
    }
}

// ---------- pass B: exclusive scan over nbuck (single block) ----------
__global__ __launch_bounds__(256) void scan_buckets(
        const unsigned* __restrict__ ghist, unsigned* __restrict__ base,
        unsigned* __restrict__ cursor, int nbuck) {
    __shared__ unsigned ts[256];
    int t = threadIdx.x;
    unsigned v[8], s = 0;
    #pragma unroll
    for (int j = 0; j < 8; ++j) {
        int idx = 8 * t + j;
        v[j] = (idx < nbuck) ? ghist[idx] : 0u;
        s += v[j];
    }
    ts[t] = s; __syncthreads();
    for (int off = 1; off < 256; off <<= 1) {
        unsigned x = (t >= off) ? ts[t - off] : 0u;
        __syncthreads();
        ts[t] += x;
        __syncthreads();
    }
    unsigned run = ts[t] - s;
    #pragma unroll
    for (int j = 0; j < 8; ++j) {
        int idx = 8 * t + j;
        if (idx < nbuck) { base[idx] = run; cursor[idx] = run; }
        run += v[j];
    }
    if (t == 255) base[nbuck] = run;   // total = nE
}

// ---------- pass C: bin edges into buckets, flattened coalesced flush ------
// payload = (dst&63)<<17 | src  (src < 2^17)
__global__ __launch_bounds__(256) void bucket_scatter(
        const int* __restrict__ src, const int* __restrict__ dst,
        unsigned* __restrict__ cursor, unsigned* __restrict__ packed,
        int nE, int nbuck) {
    __shared__ unsigned cop[MAXBUCK];           // cnt in low16, off in high16
    __shared__ unsigned short lb16[MAXBUCK];    // local base (fits u16)
    __shared__ unsigned gbase[MAXBUCK];
    __shared__ unsigned payload[SCHUNK];
    __shared__ unsigned short bid[SCHUNK];
    __shared__ unsigned ts[256];
    int t = threadIdx.x;
    int e0 = blockIdx.x * SCHUNK;
    int ec = nE - e0; if (ec > SCHUNK) ec = SCHUNK;

    for (int i = t; i < nbuck; i += 256) cop[i] = 0;
    __syncthreads();
    for (int i = t; i < ec; i += 256)
        atomicAdd(&cop[dst[e0 + i] >> BSHIFT], 1u);
    __syncthreads();
    unsigned v[8], s = 0;
    #pragma unroll
    for (int j = 0; j < 8; ++j) {
        int idx = 8 * t + j;
        v[j] = (idx < nbuck) ? (cop[idx] & 0xFFFFu) : 0u;
        s += v[j];
    }
    ts[t] = s; __syncthreads();
    for (int o = 1; o < 256; o <<= 1) {
        unsigned x = (t >= o) ? ts[t - o] : 0u;
        __syncthreads();
        ts[t] += x;
        __syncthreads();
    }
    unsigned run = ts[t] - s;
    #pragma unroll
    for (int j = 0; j < 8; ++j) {
        int idx = 8 * t + j;
        if (idx < nbuck) lb16[idx] = (unsigned short)run;
        run += v[j];
    }
    __syncthreads();
    for (int i = t; i < nbuck; i += 256) {
        unsigned c = cop[i] & 0xFFFFu;
        if (c) gbase[i] = atomicAdd(&cursor[i], c);
    }
    __syncthreads();
    for (int i = t; i < ec; i += 256) {
        int e = e0 + i;
        int d = dst[e];
        int b = d >> BSHIFT;
        unsigned p = atomicAdd(&cop[b], 0x10000u) >> 16;
        unsigned pos = (unsigned)lb16[b] + p;
        payload[pos] = ((unsigned)(d & (BNODES - 1)) << 17) | (unsigned)src[e];
        bid[pos] = (unsigned short)b;
    }
    __syncthreads();
    for (int i = t; i < ec; i += 256) {
        unsigned b = bid[i];
        packed[gbase[b] + ((unsigned)i - (unsigned)lb16[b])] = payload[i];
    }
}

// ---------- pass D: half-bucket counting sort + register packed max ---------
// block bh handles bucket b = bh>>1, nodes [ (bh&1)*32 , +32 ) within it
__global__ __launch_bounds__(256) void bucket_segmax(
        const unsigned* __restrict__ nfu,       // nf16 as dwords, 32/row
        const unsigned* __restrict__ packed,
        const unsigned* __restrict__ base,
        unsigned* __restrict__ agg16u,          // bf16 agg as dwords, 32/row
        int nN) {
    __shared__ unsigned aggS[HN * 32];          // 4 KB packed ord-bf16 max
    __shared__ unsigned sbuf[SWIN];             // 4 KB matching src indices
    __shared__ unsigned rstart[HN + 1];
    __shared__ unsigned pos[HN];
    int bh = blockIdx.x;
    int b = bh >> 1, hsel = bh & 1;
    int t = threadIdx.x;
    int wv = t >> 6, ln = t & 63;
    int half = ln >> 5, dln = ln & 31;

    for (int i = t; i < HN * 32; i += 256) aggS[i] = 0;  // minimal ord
    unsigned beg = base[b], end = base[b + 1];

    for (unsigned s0 = beg; s0 < end; s0 += SWIN) {
        unsigned scnt = end - s0; if (scnt > SWIN) scnt = SWIN;
        if (t < HN) pos[t] = 0;
        __syncthreads();
        // count entries of our half
        for (unsigned i = t; i < scnt; i += 256) {
            unsigned dL = packed[s0 + i] >> 17;
            if ((int)(dL >> 5) == hsel) atomicAdd(&pos[dL & 31], 1u);
        }
        __syncthreads();
        // wave 0: parallel exclusive scan of 32 bins via shfl
        if (t < 64) {
            int l = t & 31;
            unsigned vv = pos[l];
            unsigned x = vv;
            #pragma unroll
            for (int o = 1; o < 32; o <<= 1) {
                unsigned y = __shfl_up(x, o, 32);
                if (l >= o) x += y;
            }
            rstart[l] = x - vv;
            pos[l] = x - vv;
            if (l == 31) rstart[32] = x;
        }
        __syncthreads();
        // sort our half's entries into sbuf
        for (unsigned i = t; i < scnt; i += 256) {
            unsigned e = packed[s0 + i];
            unsigned dL = e >> 17;
            if ((int)(dL >> 5) == hsel) {
                unsigned p = atomicAdd(&pos[dL & 31], 1u);
                sbuf[p] = e & 0x1FFFFu;
            }
        }
        __syncthreads();
        // register max over contiguous runs; 2 edges/iter per accumulator,
        // unroll x2 (4 edges in flight), 2 dims/lane packed
        for (int node = wv; node < HN; node += 4) {
            unsigned rb = rstart[node], re = rstart[node + 1];
            if (rb == re) continue;
            unsigned m0 = 0, m1 = 0;
            unsigned j = rb;
            for (; j + 4 <= re; j += 4) {
                unsigned sa = sbuf[j + half];
                unsigned sb2 = sbuf[j + 2 + half];
                unsigned g0 = nfu[(size_t)sa * 32 + dln];
                unsigned g1 = nfu[(size_t)sb2 * 32 + dln];
                m0 = pkmax(m0, pk_ord_encode(g0));
                m1 = pkmax(m1, pk_ord_encode(g1));
            }
            for (; j < re; j += 2) {
                unsigned jj = j + (unsigned)half;
                if (jj < re) {
                    unsigned g = nfu[(size_t)sbuf[jj] * 32 + dln];
                    m0 = pkmax(m0, pk_ord_encode(g));
                }
            }
            unsigned m = pkmax(m0, m1);
            m = pkmax(m, __shfl_xor(m, 32, 64));    // cross-half merge
            if (ln < 32) {
                unsigned idx = node * 32 + ln;
                aggS[idx] = pkmax(aggS[idx], m);    // wave owns node
            }
        }
        __syncthreads();
    }
    // epilogue: decode, r = max(v) - x, clamp, store bf16 pair
    int n0 = b * BNODES + hsel * HN;
    for (int node = wv; node < HN; node += 4) {
        int n = n0 + node;
        if (n < nN && ln < 32) {
            unsigned raw = pk_ord_decode(aggS[node * 32 + ln]); // empty -> NaN
            unsigned xr  = nfu[(size_t)n * 32 + ln];
            float v0 = __uint_as_float(raw << 16);
            float v1 = __uint_as_float(raw & 0xFFFF0000u);
            float x0 = __uint_as_float(xr << 16);
            float x1 = __uint_as_float(xr & 0xFFFF0000u);
            float r0 = v0 - x0; r0 = (r0 >= CLAMP_V) ? r0 : 0.0f;  // NaN -> 0
            float r1 = v1 - x1; r1 = (r1 >= CLAMP_V) ? r1 : 0.0f;
            __bf16 b0 = (__bf16)r0, b1 = (__bf16)r1;
            unsigned o = ((unsigned)__builtin_bit_cast(unsigned short, b1) << 16)
                       |  (unsigned)__builtin_bit_cast(unsigned short, b0);
            agg16u[(size_t)n * 32 + ln] = o;
        }
    }
}

// ---------- pass E: MFMA MLP; W from frag-order buffer ----------
__global__ __launch_bounds__(256) void node_mlp_mfma(
        const __bf16* __restrict__ nf16,
        const __bf16* __restrict__ agg16,
        float* __restrict__ out,
        const __bf16* __restrict__ wfrag,
        const float* __restrict__ bias,
        int nTiles, int nN) {
    int lane = threadIdx.x & 63;
    int quad = lane >> 4;
    int l16  = lane & 15;
    int waveGlobal = blockIdx.x * 4 + (threadIdx.x >> 6);
    int nWaves = gridDim.x * 4;

    bf16x8 bfrag[4][4];
    #pragma unroll
    for (int c = 0; c < 4; ++c)
        #pragma unroll
        for (int ks = 0; ks < 4; ++ks)
            bfrag[c][ks] = *(const bf16x8*)(wfrag + ((size_t)((ks * 4 + c) * 64 + lane)) * 8);
    float bv[4];
    #pragma unroll
    for (int c = 0; c < 4; ++c) bv[c] = bias[c * 16 + l16];

    for (int t = waveGlobal; t < nTiles; t += nWaves) {
        int n0 = t * 16;
        int rowA = n0 + l16;
        if (rowA >= nN) rowA = nN - 1;
        const __bf16* nfr = nf16  + (size_t)rowA * D;
        const __bf16* agr = agg16 + (size_t)rowA * D;

        floatx4 acc[4] = {{0,0,0,0},{0,0,0,0},{0,0,0,0},{0,0,0,0}};
        #pragma unroll
        for (int ks = 0; ks < 4; ++ks) {
            const __bf16* p = (ks < 2) ? (nfr + ks * 32 + quad * 8)
                                       : (agr + (ks - 2) * 32 + quad * 8);
            bf16x8 a = *(const bf16x8*)p;
            #pragma unroll
            for (int c = 0; c < 4; ++c)
                acc[c] = __builtin_amdgcn_mfma_f32_16x16x32_bf16(
                             a, bfrag[c][ks], acc[c], 0, 0, 0);
        }
        #pragma unroll
        for (int r = 0; r < 4; ++r) {
            int row = n0 + quad * 4 + r;
            if (row < nN) {
                #pragma unroll
                for (int c = 0; c < 4; ++c) {
                    float vv = acc[c][r] + bv[c];
                    out[(size_t)row * D + c * 16 + l16] = fmaxf(vv, 0.0f);
                }
            }
        }
    }
}

extern "C" void kernel_launch(void* const* d_in, const int* in_sizes, int n_in,
                              void* d_out, int out_size, void* d_ws, size_t ws_size,
                              hipStream_t stream) {
    const float* nf  = (const float*)d_in[0];
    const int*   src = (const int*)d_in[1];
    const int*   dst = (const int*)d_in[2];
    const float* W   = (const float*)d_in[3];
    const float* b   = (const float*)d_in[4];
    float* out = (float*)d_out;

    int nN = in_sizes[0] / D;
    int nE = in_sizes[1];
    int nbuck = (nN + BNODES - 1) / BNODES;     // 1563

    // ws layout
    char* wsb = (char*)d_ws;
    size_t nfB  = (((size_t)nN * D * 2) + 255) & ~(size_t)255;  // 12.8 MB
    size_t pkB  = (((size_t)nE * 4)     + 255) & ~(size_t)255;  // 6.4 MB
    __bf16*   nf16   = (__bf16*)wsb;
    __bf16*   agg16  = (__bf16*)(wsb + nfB);
    unsigned* packed = (unsigned*)(wsb + 2 * nfB);
    unsigned* ghist  = (unsigned*)(wsb + 2 * nfB + pkB);
    unsigned* base   = (unsigned*)(wsb + 2 * nfB + pkB + 4 * MAXBUCK);
    unsigned* cursor = (unsigned*)(wsb + 2 * nfB + pkB + 4 * MAXBUCK + 4 * (MAXBUCK + 2));
    __bf16*   wfrag  = (__bf16*)(wsb + 2 * nfB + pkB + 4 * MAXBUCK + 8 * (MAXBUCK + 2));

    hipMemsetAsync(ghist, 0, (size_t)nbuck * 4, stream);

    int n4 = nN * D / 4;                        // 1.6M
    int convBlocks = (n4 + 255) / 256;          // 6250
    int histBlocks = (nE + HCHUNK - 1) / HCHUNK;// 391
    int gridPrep = convBlocks > histBlocks ? convBlocks : histBlocks;
    prep_kernel<<<gridPrep, 256, 0, stream>>>(nf, nf16, n4, dst, ghist, nE, nbuck,
                                              W, wfrag, histBlocks, gridPrep - 1);

    scan_buckets<<<1, 256, 0, stream>>>(ghist, base, cursor, nbuck);

    int nbS = (nE + SCHUNK - 1) / SCHUNK;       // 782
    bucket_scatter<<<nbS, 256, 0, stream>>>(src, dst, cursor, packed, nE, nbuck);

    bucket_segmax<<<nbuck * 2, 256, 0, stream>>>((const unsigned*)nf16, packed, base,
                                                 (unsigned*)agg16, nN);

    int nTiles = (nN + 15) / 16;
    node_mlp_mfma<<<768, 256, 0, stream>>>(nf16, agg16, out, wfrag, b, nTiles, nN);
}